// Round 1
// baseline (368.038 us; speedup 1.0000x reference)
//
#include <hip/hip_runtime.h>

#define NODE 1024
#define BS 8
#define IND 64
#define OUTD 64
#define DE 10
#define TD 6
#define ED 16

// ---------------------------------------------------------------------------
// K1: a[n][m] = sum_d ne[n][d] * ne[m][d]   (1024x1024, K=10)
// one block per output row n; full node_emb staged in LDS (40KB)
// ---------------------------------------------------------------------------
__global__ void k_gemm_a(const float* __restrict__ ne, float* __restrict__ a) {
    __shared__ float ne_lds[NODE * DE];
    int n = blockIdx.x;
    for (int i = threadIdx.x; i < NODE * DE; i += 256) ne_lds[i] = ne[i];
    __syncthreads();
    float nrow[DE];
#pragma unroll
    for (int d = 0; d < DE; ++d) nrow[d] = ne_lds[n * DE + d];
    for (int m = threadIdx.x; m < NODE; m += 256) {
        float s = 0.f;
#pragma unroll
        for (int d = 0; d < DE; ++d) s += nrow[d] * ne_lds[m * DE + d];
        a[n * NODE + m] = s;
    }
}

// ---------------------------------------------------------------------------
// K2: A[b][n][:] = softmax(relu(a[n][:] + dot(n_t[b], t[b])))
// one block (256 thr) per (b, n); each thread owns one float4 of the row
// ---------------------------------------------------------------------------
__global__ void k_softmax(const float* __restrict__ a, const float* __restrict__ t,
                          const float* __restrict__ nt, float* __restrict__ A) {
    int b = blockIdx.x >> 10;
    int n = blockIdx.x & 1023;
    int tid = threadIdx.x;

    float at = 0.f;
#pragma unroll
    for (int j = 0; j < TD; ++j) at += nt[b * TD + j] * t[b * TD + j];

    const float4* arow = (const float4*)(a + (size_t)n * NODE);
    float4 v = arow[tid];
    v.x = fmaxf(v.x + at, 0.f);
    v.y = fmaxf(v.y + at, 0.f);
    v.z = fmaxf(v.z + at, 0.f);
    v.w = fmaxf(v.w + at, 0.f);

    __shared__ float red[8];
    // block max
    float mx = fmaxf(fmaxf(v.x, v.y), fmaxf(v.z, v.w));
#pragma unroll
    for (int off = 32; off > 0; off >>= 1) mx = fmaxf(mx, __shfl_xor(mx, off));
    if ((tid & 63) == 0) red[tid >> 6] = mx;
    __syncthreads();
    mx = fmaxf(fmaxf(red[0], red[1]), fmaxf(red[2], red[3]));

    float4 e;
    e.x = __expf(v.x - mx);
    e.y = __expf(v.y - mx);
    e.z = __expf(v.z - mx);
    e.w = __expf(v.w - mx);
    float s = e.x + e.y + e.z + e.w;
#pragma unroll
    for (int off = 32; off > 0; off >>= 1) s += __shfl_xor(s, off);
    if ((tid & 63) == 0) red[4 + (tid >> 6)] = s;
    __syncthreads();
    s = red[4] + red[5] + red[6] + red[7];
    float inv = 1.f / s;
    e.x *= inv; e.y *= inv; e.z *= inv; e.w *= inv;

    ((float4*)(A + ((size_t)b * NODE + n) * NODE))[tid] = e;
}

// ---------------------------------------------------------------------------
// K3/K4: out = alpha * (A @ in) + beta * xres     (per batch)
// grid: 8 * 64 blocks; block = 16 rows (m) x 64 cols (o); 256 threads
// thread: og = tid&15 -> o0 = 4*og ; mloc = tid>>4 (one m row, 4 outputs)
// K staged in 64-chunks: x tile [64][64] and A tile [16][64] in LDS (padded)
// ---------------------------------------------------------------------------
__global__ void k_spmm(const float* __restrict__ Amat, const float* __restrict__ in,
                       const float* __restrict__ xres, float* __restrict__ out,
                       float alpha, float beta) {
    int b = blockIdx.x >> 6;
    int m0 = (blockIdx.x & 63) * 16;
    int tid = threadIdx.x;
    int og = tid & 15, mloc = tid >> 4;
    int o0 = og * 4;

    __shared__ float xs[64][68];
    __shared__ float As[16][68];

    const float* Ab = Amat + (size_t)b * NODE * NODE;
    const float* inb = in + (size_t)b * NODE * IND;

    float acc0 = 0.f, acc1 = 0.f, acc2 = 0.f, acc3 = 0.f;

    for (int kc = 0; kc < NODE; kc += 64) {
        // stage x tile: rows kc..kc+63, 64 cols; 16 floats per thread
        {
            int r = tid >> 2, c = (tid & 3) * 16;
            const float* src = inb + (size_t)(kc + r) * IND + c;
#pragma unroll
            for (int j = 0; j < 4; ++j) {
                float4 vv = *(const float4*)(src + 4 * j);
                *(float4*)&xs[r][c + 4 * j] = vv;
            }
        }
        // stage A tile: 16 rows x 64 cols; one float4 per thread
        {
            int mm = tid >> 4, c = (tid & 15) * 4;
            float4 vv = *(const float4*)(Ab + (size_t)(m0 + mm) * NODE + kc + c);
            *(float4*)&As[mm][c] = vv;
        }
        __syncthreads();
#pragma unroll 8
        for (int k = 0; k < 64; ++k) {
            float av = As[mloc][k];
            float4 xv = *(const float4*)&xs[k][o0];
            acc0 += av * xv.x;
            acc1 += av * xv.y;
            acc2 += av * xv.z;
            acc3 += av * xv.w;
        }
        __syncthreads();
    }

    size_t oidx = ((size_t)b * NODE + m0 + mloc) * IND + o0;
    float4 xv = *(const float4*)(xres + oidx);
    float4 r;
    r.x = alpha * acc0 + beta * xv.x;
    r.y = alpha * acc1 + beta * xv.y;
    r.z = alpha * acc2 + beta * xv.z;
    r.w = alpha * acc3 + beta * xv.w;
    *(float4*)(out + oidx) = r;
}

// ---------------------------------------------------------------------------
// K5: out[b,n,o] = sum_d emb[b,n,d] * ( sum_ki xg[b,n,ki] * W[d,ki,o] )
//                + sum_d emb[b,n,d] * bias_pool[d,o]
// xg = {x, y1, y2} (ki = k*64+i), emb = [ne[n,:10], nt[b,:6]]
// grid: 8 * 64 blocks; 16 nodes per block; 256 threads (og x mloc as above)
// ---------------------------------------------------------------------------
__global__ void k_final(const float* __restrict__ x, const float* __restrict__ y1,
                        const float* __restrict__ y2, const float* __restrict__ ne,
                        const float* __restrict__ nt, const float* __restrict__ W,
                        const float* __restrict__ bp, float* __restrict__ out) {
    int b = blockIdx.x >> 6;
    int n0 = (blockIdx.x & 63) * 16;
    int tid = threadIdx.x;
    int og = tid & 15, mloc = tid >> 4;
    int o0 = og * 4;

    __shared__ float xg[16][196];   // ki = k*64 + i (192 used, pad to 196)
    __shared__ float emb[16][16];

    // stage x_g rows for the block's 16 nodes
    {
        int m = tid >> 4, i0 = (tid & 15) * 4;
        size_t roff = ((size_t)b * NODE + n0 + m) * IND + i0;
        float4 v0 = *(const float4*)(x + roff);
        float4 v1 = *(const float4*)(y1 + roff);
        float4 v2 = *(const float4*)(y2 + roff);
        *(float4*)&xg[m][0 * 64 + i0] = v0;
        *(float4*)&xg[m][1 * 64 + i0] = v1;
        *(float4*)&xg[m][2 * 64 + i0] = v2;
    }
    // stage emb
    {
        int m = tid >> 4, d = tid & 15;
        emb[m][d] = (d < DE) ? ne[(n0 + m) * DE + d] : nt[b * TD + (d - DE)];
    }
    __syncthreads();

    float acc0 = 0.f, acc1 = 0.f, acc2 = 0.f, acc3 = 0.f;
    for (int d = 0; d < ED; ++d) {
        float t0 = 0.f, t1 = 0.f, t2 = 0.f, t3 = 0.f;
        const float* Wd = W + (size_t)d * 192 * 64;
#pragma unroll 4
        for (int ki = 0; ki < 192; ++ki) {
            float4 w = *(const float4*)(Wd + ki * 64 + o0);
            float av = xg[mloc][ki];
            t0 += av * w.x;
            t1 += av * w.y;
            t2 += av * w.z;
            t3 += av * w.w;
        }
        float e = emb[mloc][d];
        acc0 += e * t0; acc1 += e * t1; acc2 += e * t2; acc3 += e * t3;
    }
#pragma unroll
    for (int d = 0; d < ED; ++d) {
        float e = emb[mloc][d];
        float4 bv = *(const float4*)(bp + d * 64 + o0);
        acc0 += e * bv.x; acc1 += e * bv.y; acc2 += e * bv.z; acc3 += e * bv.w;
    }

    size_t oidx = ((size_t)b * NODE + n0 + mloc) * OUTD + o0;
    *(float4*)(out + oidx) = make_float4(acc0, acc1, acc2, acc3);
}

// ---------------------------------------------------------------------------
extern "C" void kernel_launch(void* const* d_in, const int* in_sizes, int n_in,
                              void* d_out, int out_size, void* d_ws, size_t ws_size,
                              hipStream_t stream) {
    const float* x  = (const float*)d_in[0];   // [8,1024,64]
    const float* ne = (const float*)d_in[1];   // [1024,10]
    const float* t  = (const float*)d_in[2];   // [8,6]
    const float* nt = (const float*)d_in[3];   // [8,6]
    // d_in[4] = p (unused, period=False branch)
    const float* W  = (const float*)d_in[5];   // [16,3,64,64]
    const float* bp = (const float*)d_in[6];   // [16,64]
    float* out = (float*)d_out;                // [8,1024,64]

    float* ws = (float*)d_ws;
    float* a  = ws;                                   // 1M floats (4MB)
    float* A  = ws + (1u << 20);                      // 8M floats (32MB)
    float* y1 = ws + (1u << 20) + (8u << 20);         // 512K floats
    float* y2 = y1 + (1u << 19);                      // 512K floats

    k_gemm_a<<<NODE, 256, 0, stream>>>(ne, a);
    k_softmax<<<BS * NODE, 256, 0, stream>>>(a, t, nt, A);
    k_spmm<<<BS * (NODE / 16), 256, 0, stream>>>(A, x, x, y1, 1.0f, 0.0f);
    k_spmm<<<BS * (NODE / 16), 256, 0, stream>>>(A, y1, x, y2, 2.0f, -1.0f);
    k_final<<<BS * (NODE / 16), 256, 0, stream>>>(x, y1, y2, ne, nt, W, bp, out);
}

// Round 2
// 237.284 us; speedup vs baseline: 1.5510x; 1.5510x over previous
//
#include <hip/hip_runtime.h>
#include <hip/hip_bf16.h>

#define NODE 1024
#define BS 8
#define IND 64
#define OUTD 64
#define DE 10
#define TD 6
#define ED 16

struct alignas(8) bf4 { __hip_bfloat16 a, b, c, d; };

// ---------------------------------------------------------------------------
// K1: a[n][m] = sum_d ne[n][d] * ne[m][d]   (1024x1024, K=10)
// ---------------------------------------------------------------------------
__global__ void k_gemm_a(const float* __restrict__ ne, float* __restrict__ a) {
    __shared__ float ne_lds[NODE * DE];
    int n = blockIdx.x;
    for (int i = threadIdx.x; i < NODE * DE; i += 256) ne_lds[i] = ne[i];
    __syncthreads();
    float nrow[DE];
#pragma unroll
    for (int d = 0; d < DE; ++d) nrow[d] = ne_lds[n * DE + d];
    for (int m = threadIdx.x; m < NODE; m += 256) {
        float s = 0.f;
#pragma unroll
        for (int d = 0; d < DE; ++d) s += nrow[d] * ne_lds[m * DE + d];
        a[n * NODE + m] = s;
    }
}

// ---------------------------------------------------------------------------
// K2: A[b][n][:] = softmax(relu(a[n][:] + dot(n_t[b], t[b])))
// ---------------------------------------------------------------------------
__global__ void k_softmax(const float* __restrict__ a, const float* __restrict__ t,
                          const float* __restrict__ nt, float* __restrict__ A) {
    int b = blockIdx.x >> 10;
    int n = blockIdx.x & 1023;
    int tid = threadIdx.x;

    float at = 0.f;
#pragma unroll
    for (int j = 0; j < TD; ++j) at += nt[b * TD + j] * t[b * TD + j];

    const float4* arow = (const float4*)(a + (size_t)n * NODE);
    float4 v = arow[tid];
    v.x = fmaxf(v.x + at, 0.f);
    v.y = fmaxf(v.y + at, 0.f);
    v.z = fmaxf(v.z + at, 0.f);
    v.w = fmaxf(v.w + at, 0.f);

    __shared__ float red[8];
    float mx = fmaxf(fmaxf(v.x, v.y), fmaxf(v.z, v.w));
#pragma unroll
    for (int off = 32; off > 0; off >>= 1) mx = fmaxf(mx, __shfl_xor(mx, off));
    if ((tid & 63) == 0) red[tid >> 6] = mx;
    __syncthreads();
    mx = fmaxf(fmaxf(red[0], red[1]), fmaxf(red[2], red[3]));

    float4 e;
    e.x = __expf(v.x - mx);
    e.y = __expf(v.y - mx);
    e.z = __expf(v.z - mx);
    e.w = __expf(v.w - mx);
    float s = e.x + e.y + e.z + e.w;
#pragma unroll
    for (int off = 32; off > 0; off >>= 1) s += __shfl_xor(s, off);
    if ((tid & 63) == 0) red[4 + (tid >> 6)] = s;
    __syncthreads();
    s = red[4] + red[5] + red[6] + red[7];
    float inv = 1.f / s;
    e.x *= inv; e.y *= inv; e.z *= inv; e.w *= inv;

    ((float4*)(A + ((size_t)b * NODE + n) * NODE))[tid] = e;
}

// ---------------------------------------------------------------------------
// K3/K4: out = alpha * (A @ in) + beta * xres   (per batch)
// 32 rows x 64 cols per block; 256 thr: og=tid&15 (4 cols), mg=tid>>4 (2 rows)
// A tile staged TRANSPOSED (AsT[k][m]) so inner loop reads float2 of rows.
// ---------------------------------------------------------------------------
__global__ void k_spmm(const float* __restrict__ Amat, const float* __restrict__ in,
                       const float* __restrict__ xres, float* __restrict__ out,
                       float alpha, float beta) {
    int b = blockIdx.x >> 5;
    int m0 = (blockIdx.x & 31) * 32;
    int tid = threadIdx.x;
    int og = tid & 15, mg = tid >> 4;
    int o0 = og * 4;

    __shared__ float xs[64][68];
    __shared__ float AsT[64][36];

    const float* Ab = Amat + (size_t)b * NODE * NODE;
    const float* inb = in + (size_t)b * NODE * IND;

    float acc[2][4];
#pragma unroll
    for (int j = 0; j < 2; ++j)
#pragma unroll
        for (int c = 0; c < 4; ++c) acc[j][c] = 0.f;

    for (int kc = 0; kc < NODE; kc += 64) {
        // stage x tile: rows kc..kc+63 x 64 cols
        {
            int r = tid >> 2, c = (tid & 3) * 16;
            const float* src = inb + (size_t)(kc + r) * IND + c;
#pragma unroll
            for (int j = 0; j < 4; ++j)
                *(float4*)&xs[r][c + 4 * j] = *(const float4*)(src + 4 * j);
        }
        // stage A tile transposed: 32 rows x 64 k -> AsT[k][m]
        {
            int r = tid >> 3, k0 = (tid & 7) * 8;
            const float* src = Ab + (size_t)(m0 + r) * NODE + kc + k0;
            float4 v0 = *(const float4*)(src);
            float4 v1 = *(const float4*)(src + 4);
            AsT[k0 + 0][r] = v0.x; AsT[k0 + 1][r] = v0.y;
            AsT[k0 + 2][r] = v0.z; AsT[k0 + 3][r] = v0.w;
            AsT[k0 + 4][r] = v1.x; AsT[k0 + 5][r] = v1.y;
            AsT[k0 + 6][r] = v1.z; AsT[k0 + 7][r] = v1.w;
        }
        __syncthreads();
#pragma unroll 8
        for (int k = 0; k < 64; ++k) {
            float2 av = *(const float2*)&AsT[k][mg * 2];
            float4 xv = *(const float4*)&xs[k][o0];
            acc[0][0] += av.x * xv.x; acc[0][1] += av.x * xv.y;
            acc[0][2] += av.x * xv.z; acc[0][3] += av.x * xv.w;
            acc[1][0] += av.y * xv.x; acc[1][1] += av.y * xv.y;
            acc[1][2] += av.y * xv.z; acc[1][3] += av.y * xv.w;
        }
        __syncthreads();
    }

#pragma unroll
    for (int j = 0; j < 2; ++j) {
        size_t oidx = ((size_t)b * NODE + m0 + mg * 2 + j) * IND + o0;
        float4 xv = *(const float4*)(xres + oidx);
        float4 r;
        r.x = alpha * acc[j][0] + beta * xv.x;
        r.y = alpha * acc[j][1] + beta * xv.y;
        r.z = alpha * acc[j][2] + beta * xv.z;
        r.w = alpha * acc[j][3] + beta * xv.w;
        *(float4*)(out + oidx) = r;
    }
}

// ---------------------------------------------------------------------------
// K5: Wn[n,ki,o] = sum_{d<10} ne[n,d] * W[d,ki,o]   (bf16 output, 25MB)
// grid = 64 node-tiles x 12 ki/o-blocks. Thread owns one (ki,o4) for 16 nodes.
// ---------------------------------------------------------------------------
__global__ void k_wn(const float* __restrict__ ne, const float* __restrict__ W,
                     bf4* __restrict__ Wn) {
    int ntile = blockIdx.x / 12;
    int kob = blockIdx.x % 12;
    int tid = threadIdx.x;
    int idx = kob * 256 + tid;      // 0..3071
    int ki = idx >> 4;              // 0..191
    int og = idx & 15;              // o0 = og*4

    __shared__ float ne_l[16][DE];
    if (tid < 16 * DE) ne_l[tid / DE][tid % DE] = ne[(ntile * 16 + tid / DE) * DE + tid % DE];
    __syncthreads();

    float acc[16][4];
#pragma unroll
    for (int n = 0; n < 16; ++n)
#pragma unroll
        for (int c = 0; c < 4; ++c) acc[n][c] = 0.f;

#pragma unroll
    for (int d = 0; d < DE; ++d) {
        float4 wv = *(const float4*)&W[((size_t)d * 192 + ki) * 64 + og * 4];
#pragma unroll
        for (int n = 0; n < 16; ++n) {
            float e = ne_l[n][d];
            acc[n][0] += e * wv.x; acc[n][1] += e * wv.y;
            acc[n][2] += e * wv.z; acc[n][3] += e * wv.w;
        }
    }

#pragma unroll
    for (int n = 0; n < 16; ++n) {
        bf4 v;
        v.a = __float2bfloat16(acc[n][0]);
        v.b = __float2bfloat16(acc[n][1]);
        v.c = __float2bfloat16(acc[n][2]);
        v.d = __float2bfloat16(acc[n][3]);
        Wn[(((size_t)(ntile * 16 + n)) * 192 + ki) * 16 + og] = v;
    }
}

// ---------------------------------------------------------------------------
// K6: Wb[b,ki,o] = sum_{dd<6} nt[b,dd] * W[10+dd,ki,o]   (fp32, 393KB)
// ---------------------------------------------------------------------------
__global__ void k_wb(const float* __restrict__ nt, const float* __restrict__ W,
                     float* __restrict__ Wb) {
    int idx = blockIdx.x * 256 + threadIdx.x;   // 0..24575
    int b = idx / 3072;
    int r = idx % 3072;
    int ki = r >> 4;
    int og = r & 15;

    float4 acc = make_float4(0.f, 0.f, 0.f, 0.f);
#pragma unroll
    for (int dd = 0; dd < TD; ++dd) {
        float e = nt[b * TD + dd];
        float4 wv = *(const float4*)&W[((size_t)(DE + dd) * 192 + ki) * 64 + og * 4];
        acc.x += e * wv.x; acc.y += e * wv.y; acc.z += e * wv.z; acc.w += e * wv.w;
    }
    *(float4*)&Wb[((size_t)b * 192 + ki) * 64 + og * 4] = acc;
}

// ---------------------------------------------------------------------------
// K7: out[b,n,o] = sum_ki xg[b,n,ki]*Wn[n,ki,o] + sum_ki xg*Wb[b,ki,o] + bias
// block = 2 nodes x 8 batches x 64 outs; 512 blocks.
// thread: og=tid&15, b=(tid>>4)&7, nl=tid>>7
// ---------------------------------------------------------------------------
__global__ void k_out(const float* __restrict__ x, const float* __restrict__ y1,
                      const float* __restrict__ y2, const bf4* __restrict__ Wn,
                      const float* __restrict__ Wb, const float* __restrict__ ne,
                      const float* __restrict__ nt, const float* __restrict__ bp,
                      float* __restrict__ out) {
    int n0 = blockIdx.x * 2;
    int tid = threadIdx.x;
    int og = tid & 15, b = (tid >> 4) & 7, nl = tid >> 7;
    int o0 = og * 4;

    __shared__ float xg_l[2][BS][192];
    // stage xg for the block's 2 nodes x 8 batches
    for (int idx = tid; idx < 2 * BS * 192; idx += 256) {
        int nb = idx / 192;          // 0..15
        int bb = nb >> 1, nn = nb & 1;
        int ki = idx % 192;
        int src = ki >> 6, i = ki & 63;
        const float* p = (src == 0) ? x : (src == 1) ? y1 : y2;
        xg_l[nn][bb][ki] = p[((size_t)bb * NODE + n0 + nn) * IND + i];
    }
    __syncthreads();

    int n = n0 + nl;
    float acc0 = 0.f, acc1 = 0.f, acc2 = 0.f, acc3 = 0.f;

    // node part: Wn[n] (bf16), shared by all 8 batches via L1
    const bf4* WnRow = Wn + (size_t)n * 192 * 16 + og;
#pragma unroll 4
    for (int ki = 0; ki < 192; ++ki) {
        float xv = xg_l[nl][b][ki];
        bf4 w = WnRow[ki * 16];
        acc0 += xv * __bfloat162float(w.a);
        acc1 += xv * __bfloat162float(w.b);
        acc2 += xv * __bfloat162float(w.c);
        acc3 += xv * __bfloat162float(w.d);
    }

    // batch part
    const float* WbRow = Wb + (size_t)b * 192 * 64 + o0;
#pragma unroll 4
    for (int ki = 0; ki < 192; ++ki) {
        float xv = xg_l[nl][b][ki];
        float4 w = *(const float4*)&WbRow[ki * 64];
        acc0 += xv * w.x; acc1 += xv * w.y; acc2 += xv * w.z; acc3 += xv * w.w;
    }

    // bias
#pragma unroll
    for (int d = 0; d < DE; ++d) {
        float e = ne[n * DE + d];
        float4 bv = *(const float4*)&bp[d * 64 + o0];
        acc0 += e * bv.x; acc1 += e * bv.y; acc2 += e * bv.z; acc3 += e * bv.w;
    }
#pragma unroll
    for (int dd = 0; dd < TD; ++dd) {
        float e = nt[b * TD + dd];
        float4 bv = *(const float4*)&bp[(DE + dd) * 64 + o0];
        acc0 += e * bv.x; acc1 += e * bv.y; acc2 += e * bv.z; acc3 += e * bv.w;
    }

    *(float4*)&out[((size_t)b * NODE + n) * OUTD + o0] = make_float4(acc0, acc1, acc2, acc3);
}

// ---------------------------------------------------------------------------
extern "C" void kernel_launch(void* const* d_in, const int* in_sizes, int n_in,
                              void* d_out, int out_size, void* d_ws, size_t ws_size,
                              hipStream_t stream) {
    const float* x  = (const float*)d_in[0];   // [8,1024,64]
    const float* ne = (const float*)d_in[1];   // [1024,10]
    const float* t  = (const float*)d_in[2];   // [8,6]
    const float* nt = (const float*)d_in[3];   // [8,6]
    const float* W  = (const float*)d_in[5];   // [16,3,64,64]
    const float* bp = (const float*)d_in[6];   // [16,64]
    float* out = (float*)d_out;                // [8,1024,64]

    float* ws = (float*)d_ws;
    float* a   = ws;                                  // 1M floats
    float* A   = ws + (1u << 20);                     // 8M floats
    float* y1  = A + (8u << 20);                      // 512K floats
    float* y2  = y1 + (1u << 19);                     // 512K floats
    float* Wb  = y2 + (1u << 19);                     // 98304 floats
    bf4*   Wn  = (bf4*)(Wb + 98304);                  // 1024*192*16 bf4 (25MB)

    k_gemm_a<<<NODE, 256, 0, stream>>>(ne, a);
    k_softmax<<<BS * NODE, 256, 0, stream>>>(a, t, nt, A);
    k_spmm<<<BS * (NODE / 32), 256, 0, stream>>>(A, x, x, y1, 1.0f, 0.0f);
    k_spmm<<<BS * (NODE / 32), 256, 0, stream>>>(A, y1, x, y2, 2.0f, -1.0f);
    k_wn<<<64 * 12, 256, 0, stream>>>(ne, W, Wn);
    k_wb<<<96, 256, 0, stream>>>(nt, W, Wb);
    k_out<<<NODE / 2, 256, 0, stream>>>(x, y1, y2, Wn, Wb, ne, nt, bp, out);
}

// Round 3
// 154.806 us; speedup vs baseline: 2.3774x; 1.5328x over previous
//
#include <hip/hip_runtime.h>
#include <hip/hip_bf16.h>

#define NODE 1024
#define BS 8
#define IND 64
#define OUTD 64
#define DE 10
#define TD 6
#define ED 16

struct alignas(8) bf4 { __hip_bfloat16 a, b, c, d; };
typedef short short8 __attribute__((ext_vector_type(8)));
typedef float f32x16 __attribute__((ext_vector_type(16)));

// ---------------------------------------------------------------------------
// K1: a[n][m] = sum_d ne[n][d] * ne[m][d]   (1024x1024, K=10)
// ---------------------------------------------------------------------------
__global__ void k_gemm_a(const float* __restrict__ ne, float* __restrict__ a) {
    __shared__ float ne_lds[NODE * DE];
    int n = blockIdx.x;
    for (int i = threadIdx.x; i < NODE * DE; i += 256) ne_lds[i] = ne[i];
    __syncthreads();
    float nrow[DE];
#pragma unroll
    for (int d = 0; d < DE; ++d) nrow[d] = ne_lds[n * DE + d];
    for (int m = threadIdx.x; m < NODE; m += 256) {
        float s = 0.f;
#pragma unroll
        for (int d = 0; d < DE; ++d) s += nrow[d] * ne_lds[m * DE + d];
        a[n * NODE + m] = s;
    }
}

// ---------------------------------------------------------------------------
// K2: A16[b][n][:] = bf16(softmax(relu(a[n][:] + dot(n_t[b], t[b]))))
// ---------------------------------------------------------------------------
__global__ void k_softmax(const float* __restrict__ a, const float* __restrict__ t,
                          const float* __restrict__ nt, __hip_bfloat16* __restrict__ A16) {
    int b = blockIdx.x >> 10;
    int n = blockIdx.x & 1023;
    int tid = threadIdx.x;

    float at = 0.f;
#pragma unroll
    for (int j = 0; j < TD; ++j) at += nt[b * TD + j] * t[b * TD + j];

    const float4* arow = (const float4*)(a + (size_t)n * NODE);
    float4 v = arow[tid];
    v.x = fmaxf(v.x + at, 0.f);
    v.y = fmaxf(v.y + at, 0.f);
    v.z = fmaxf(v.z + at, 0.f);
    v.w = fmaxf(v.w + at, 0.f);

    __shared__ float red[8];
    float mx = fmaxf(fmaxf(v.x, v.y), fmaxf(v.z, v.w));
#pragma unroll
    for (int off = 32; off > 0; off >>= 1) mx = fmaxf(mx, __shfl_xor(mx, off));
    if ((tid & 63) == 0) red[tid >> 6] = mx;
    __syncthreads();
    mx = fmaxf(fmaxf(red[0], red[1]), fmaxf(red[2], red[3]));

    float4 e;
    e.x = __expf(v.x - mx);
    e.y = __expf(v.y - mx);
    e.z = __expf(v.z - mx);
    e.w = __expf(v.w - mx);
    float s = e.x + e.y + e.z + e.w;
#pragma unroll
    for (int off = 32; off > 0; off >>= 1) s += __shfl_xor(s, off);
    if ((tid & 63) == 0) red[4 + (tid >> 6)] = s;
    __syncthreads();
    s = red[4] + red[5] + red[6] + red[7];
    float inv = 1.f / s;

    bf4 o;
    o.a = __float2bfloat16(e.x * inv);
    o.b = __float2bfloat16(e.y * inv);
    o.c = __float2bfloat16(e.z * inv);
    o.d = __float2bfloat16(e.w * inv);
    ((bf4*)(A16 + (((size_t)(b << 10) + n) << 10)))[tid] = o;
}

// ---------------------------------------------------------------------------
// K2b: xT[b][f][node] = bf16(x[b][node][f])  (transpose+convert, 1MB out)
// ---------------------------------------------------------------------------
__global__ void k_prep(const float* __restrict__ x, __hip_bfloat16* __restrict__ xT) {
    int b = blockIdx.x >> 4;
    int n0 = (blockIdx.x & 15) * 64;
    __shared__ __hip_bfloat16 T[64][72];
    int tid = threadIdx.x;
    {
        int n = tid >> 2, f0 = (tid & 3) * 16;
        const float* src = x + (((size_t)(b << 10)) + n0 + n) * 64 + f0;
#pragma unroll
        for (int j = 0; j < 16; ++j) T[f0 + j][n] = __float2bfloat16(src[j]);
    }
    __syncthreads();
    {
        int f = tid >> 2, c0 = (tid & 3) * 16;
        __hip_bfloat16* dst = xT + ((size_t)b * 64 + f) * 1024 + n0 + c0;
#pragma unroll
        for (int j = 0; j < 16; ++j) dst[j] = T[f][c0 + j];
    }
}

// ---------------------------------------------------------------------------
// K3/K4: MFMA spmm.  D[feat][node] = srcT(64xK) x A^T  via
//   mfma_f32_32x32x16_bf16( Afrag = srcT rows, Bfrag = Amat rows )
// block = 128 thr = 2 waves (fh=wave); 32-node tile; grid = 8*32 = 256.
// FIRST: yout = acc (fp32) and youtT = bf16(acc) transposed.
// !FIRST: yout = 2*acc - xres.
// LDS-free: fragments are contiguous 16B global loads, L1/L2 do the reuse.
// ---------------------------------------------------------------------------
template<bool FIRST>
__global__ void k_spmm_mfma(const __hip_bfloat16* __restrict__ A16,
                            const __hip_bfloat16* __restrict__ srcT,
                            const float* __restrict__ xres,
                            float* __restrict__ yout,
                            __hip_bfloat16* __restrict__ youtT) {
    int b = blockIdx.x >> 5;
    int n0 = (blockIdx.x & 31) * 32;
    int tid = threadIdx.x;
    int fh = tid >> 6;          // wave id: feature half
    int lane = tid & 63;
    int l31 = lane & 31, hi = lane >> 5;

    const __hip_bfloat16* pa = srcT + ((size_t)b * 64 + fh * 32 + l31) * 1024 + hi * 8;
    const __hip_bfloat16* pb = A16 + ((size_t)b << 20) + (size_t)(n0 + l31) * 1024 + hi * 8;

    f32x16 acc0, acc1;
#pragma unroll
    for (int i = 0; i < 16; ++i) { acc0[i] = 0.f; acc1[i] = 0.f; }

    short8 ac[4], bc[4];
#pragma unroll
    for (int j = 0; j < 4; ++j) {
        ac[j] = *(const short8*)(pa + j * 16);
        bc[j] = *(const short8*)(pb + j * 16);
    }
    for (int g = 1; g < 16; ++g) {
        short8 an[4], bn[4];
#pragma unroll
        for (int j = 0; j < 4; ++j) {
            an[j] = *(const short8*)(pa + g * 64 + j * 16);
            bn[j] = *(const short8*)(pb + g * 64 + j * 16);
        }
        acc0 = __builtin_amdgcn_mfma_f32_32x32x16_bf16(ac[0], bc[0], acc0, 0, 0, 0);
        acc1 = __builtin_amdgcn_mfma_f32_32x32x16_bf16(ac[1], bc[1], acc1, 0, 0, 0);
        acc0 = __builtin_amdgcn_mfma_f32_32x32x16_bf16(ac[2], bc[2], acc0, 0, 0, 0);
        acc1 = __builtin_amdgcn_mfma_f32_32x32x16_bf16(ac[3], bc[3], acc1, 0, 0, 0);
#pragma unroll
        for (int j = 0; j < 4; ++j) { ac[j] = an[j]; bc[j] = bn[j]; }
    }
    acc0 = __builtin_amdgcn_mfma_f32_32x32x16_bf16(ac[0], bc[0], acc0, 0, 0, 0);
    acc1 = __builtin_amdgcn_mfma_f32_32x32x16_bf16(ac[1], bc[1], acc1, 0, 0, 0);
    acc0 = __builtin_amdgcn_mfma_f32_32x32x16_bf16(ac[2], bc[2], acc0, 0, 0, 0);
    acc1 = __builtin_amdgcn_mfma_f32_32x32x16_bf16(ac[3], bc[3], acc1, 0, 0, 0);

#pragma unroll
    for (int i = 0; i < 16; ++i) acc0[i] += acc1[i];

    int node = n0 + l31;
    // D layout: col(=node)=lane&31, row(=feat)=(r&3)+8*(r>>2)+4*hi
#pragma unroll
    for (int rg = 0; rg < 4; ++rg) {
        int fb = fh * 32 + hi * 4 + rg * 8;
        float4 v = make_float4(acc0[rg * 4], acc0[rg * 4 + 1], acc0[rg * 4 + 2], acc0[rg * 4 + 3]);
        size_t off = (((size_t)(b << 10)) + node) * 64 + fb;
        if (FIRST) {
            *(float4*)(yout + off) = v;
        } else {
            float4 xv = *(const float4*)(xres + off);
            v.x = 2.f * v.x - xv.x;
            v.y = 2.f * v.y - xv.y;
            v.z = 2.f * v.z - xv.z;
            v.w = 2.f * v.w - xv.w;
            *(float4*)(yout + off) = v;
        }
    }
    if (FIRST) {
#pragma unroll
        for (int r = 0; r < 16; ++r) {
            int f = fh * 32 + hi * 4 + (r >> 2) * 8 + (r & 3);
            youtT[((size_t)b * 64 + f) * 1024 + node] = __float2bfloat16(acc0[r]);
        }
    }
}

// ---------------------------------------------------------------------------
// K5: Wn[n,ki,o] = sum_{d<10} ne[n,d] * W[d,ki,o]   (bf16 output, 25MB)
// ---------------------------------------------------------------------------
__global__ void k_wn(const float* __restrict__ ne, const float* __restrict__ W,
                     bf4* __restrict__ Wn) {
    int ntile = blockIdx.x / 12;
    int kob = blockIdx.x % 12;
    int tid = threadIdx.x;
    int idx = kob * 256 + tid;      // 0..3071
    int ki = idx >> 4;              // 0..191
    int og = idx & 15;              // o0 = og*4

    __shared__ float ne_l[16][DE];
    if (tid < 16 * DE) ne_l[tid / DE][tid % DE] = ne[(ntile * 16 + tid / DE) * DE + tid % DE];
    __syncthreads();

    float acc[16][4];
#pragma unroll
    for (int n = 0; n < 16; ++n)
#pragma unroll
        for (int c = 0; c < 4; ++c) acc[n][c] = 0.f;

#pragma unroll
    for (int d = 0; d < DE; ++d) {
        float4 wv = *(const float4*)&W[((size_t)d * 192 + ki) * 64 + og * 4];
#pragma unroll
        for (int n = 0; n < 16; ++n) {
            float e = ne_l[n][d];
            acc[n][0] += e * wv.x; acc[n][1] += e * wv.y;
            acc[n][2] += e * wv.z; acc[n][3] += e * wv.w;
        }
    }

#pragma unroll
    for (int n = 0; n < 16; ++n) {
        bf4 v;
        v.a = __float2bfloat16(acc[n][0]);
        v.b = __float2bfloat16(acc[n][1]);
        v.c = __float2bfloat16(acc[n][2]);
        v.d = __float2bfloat16(acc[n][3]);
        Wn[(((size_t)(ntile * 16 + n)) * 192 + ki) * 16 + og] = v;
    }
}

// ---------------------------------------------------------------------------
// K6: Wb[b,ki,o] = sum_{dd<6} nt[b,dd] * W[10+dd,ki,o]   (fp32, 393KB)
// ---------------------------------------------------------------------------
__global__ void k_wb(const float* __restrict__ nt, const float* __restrict__ W,
                     float* __restrict__ Wb) {
    int idx = blockIdx.x * 256 + threadIdx.x;   // 0..24575
    int b = idx / 3072;
    int r = idx % 3072;
    int ki = r >> 4;
    int og = r & 15;

    float4 acc = make_float4(0.f, 0.f, 0.f, 0.f);
#pragma unroll
    for (int dd = 0; dd < TD; ++dd) {
        float e = nt[b * TD + dd];
        float4 wv = *(const float4*)&W[((size_t)(DE + dd) * 192 + ki) * 64 + og * 4];
        acc.x += e * wv.x; acc.y += e * wv.y; acc.z += e * wv.z; acc.w += e * wv.w;
    }
    *(float4*)&Wb[((size_t)b * 192 + ki) * 64 + og * 4] = acc;
}

// ---------------------------------------------------------------------------
// K7: out[b,n,o] = sum_ki xg[b,n,ki]*Wn[n,ki,o] + sum_ki xg*Wb[b,ki,o] + bias
// ---------------------------------------------------------------------------
__global__ void k_out(const float* __restrict__ x, const float* __restrict__ y1,
                      const float* __restrict__ y2, const bf4* __restrict__ Wn,
                      const float* __restrict__ Wb, const float* __restrict__ ne,
                      const float* __restrict__ nt, const float* __restrict__ bp,
                      float* __restrict__ out) {
    int n0 = blockIdx.x * 2;
    int tid = threadIdx.x;
    int og = tid & 15, b = (tid >> 4) & 7, nl = tid >> 7;
    int o0 = og * 4;

    __shared__ float xg_l[2][BS][192];
    for (int idx = tid; idx < 2 * BS * 192; idx += 256) {
        int nb = idx / 192;
        int bb = nb >> 1, nn = nb & 1;
        int ki = idx % 192;
        int src = ki >> 6, i = ki & 63;
        const float* p = (src == 0) ? x : (src == 1) ? y1 : y2;
        xg_l[nn][bb][ki] = p[((size_t)bb * NODE + n0 + nn) * IND + i];
    }
    __syncthreads();

    int n = n0 + nl;
    float acc0 = 0.f, acc1 = 0.f, acc2 = 0.f, acc3 = 0.f;

    const bf4* WnRow = Wn + (size_t)n * 192 * 16 + og;
#pragma unroll 4
    for (int ki = 0; ki < 192; ++ki) {
        float xv = xg_l[nl][b][ki];
        bf4 w = WnRow[ki * 16];
        acc0 += xv * __bfloat162float(w.a);
        acc1 += xv * __bfloat162float(w.b);
        acc2 += xv * __bfloat162float(w.c);
        acc3 += xv * __bfloat162float(w.d);
    }

    const float* WbRow = Wb + (size_t)b * 192 * 64 + o0;
#pragma unroll 4
    for (int ki = 0; ki < 192; ++ki) {
        float xv = xg_l[nl][b][ki];
        float4 w = *(const float4*)&WbRow[ki * 64];
        acc0 += xv * w.x; acc1 += xv * w.y; acc2 += xv * w.z; acc3 += xv * w.w;
    }

#pragma unroll
    for (int d = 0; d < DE; ++d) {
        float e = ne[n * DE + d];
        float4 bv = *(const float4*)&bp[d * 64 + o0];
        acc0 += e * bv.x; acc1 += e * bv.y; acc2 += e * bv.z; acc3 += e * bv.w;
    }
#pragma unroll
    for (int dd = 0; dd < TD; ++dd) {
        float e = nt[b * TD + dd];
        float4 bv = *(const float4*)&bp[(DE + dd) * 64 + o0];
        acc0 += e * bv.x; acc1 += e * bv.y; acc2 += e * bv.z; acc3 += e * bv.w;
    }

    *(float4*)&out[((size_t)b * NODE + n) * OUTD + o0] = make_float4(acc0, acc1, acc2, acc3);
}

// ---------------------------------------------------------------------------
extern "C" void kernel_launch(void* const* d_in, const int* in_sizes, int n_in,
                              void* d_out, int out_size, void* d_ws, size_t ws_size,
                              hipStream_t stream) {
    const float* x  = (const float*)d_in[0];   // [8,1024,64]
    const float* ne = (const float*)d_in[1];   // [1024,10]
    const float* t  = (const float*)d_in[2];   // [8,6]
    const float* nt = (const float*)d_in[3];   // [8,6]
    const float* W  = (const float*)d_in[5];   // [16,3,64,64]
    const float* bp = (const float*)d_in[6];   // [16,64]
    float* out = (float*)d_out;                // [8,1024,64]

    float* ws = (float*)d_ws;
    float* a = ws;                                     // 1M f32
    __hip_bfloat16* A16 = (__hip_bfloat16*)(ws + (1u << 20));   // 8M bf16
    float* y1 = ws + (1u << 20) + (1u << 22);          // 512K f32
    float* y2 = y1 + (1u << 19);                       // 512K f32
    float* Wb = y2 + (1u << 19);                       // 98304 f32
    bf4*   Wn = (bf4*)(Wb + 98304);                    // 3,145,728 bf4 (25MB)
    __hip_bfloat16* xT  = (__hip_bfloat16*)((float*)Wn + 6291456);  // 512K bf16
    __hip_bfloat16* y1T = xT + (512u << 10);           // 512K bf16

    k_gemm_a<<<NODE, 256, 0, stream>>>(ne, a);
    k_softmax<<<BS * NODE, 256, 0, stream>>>(a, t, nt, A16);
    k_prep<<<BS * 16, 256, 0, stream>>>(x, xT);
    k_spmm_mfma<true ><<<BS * 32, 128, 0, stream>>>(A16, xT,  x, y1, y1T);
    k_spmm_mfma<false><<<BS * 32, 128, 0, stream>>>(A16, y1T, x, y2, nullptr);
    k_wn<<<64 * 12, 256, 0, stream>>>(ne, W, Wn);
    k_wb<<<96, 256, 0, stream>>>(nt, W, Wb);
    k_out<<<NODE / 2, 256, 0, stream>>>(x, y1, y2, Wn, Wb, ne, nt, bp, out);
}